// Round 1
// baseline (198.468 us; speedup 1.0000x reference)
//
#include <hip/hip_runtime.h>

// Problem constants
#define CIN   128
#define COUT  64
#define KK    64
#define HW    16384   // 128*128
#define NB1   256     // K1 compute blocks (128 per batch)

// Workspace layout (float offsets)
#define OFF_XT    0u          // [2][64][16384]  xt
#define OFF_PS    2097152u    // [256][64][64]   partial bin sums
#define OFF_PC    3145728u    // [256][64]       partial bin counts
#define OFF_MEANS 3162112u    // [2][64][64]
#define OFF_DIAG  3170304u    // [2][64]         m^T C^-1 m
#define OFF_INV   3170432u    // [64][64]        inv(cov)
#define OFF_ADJM  3174528u    // [2][64][64]     adj @ means
#define OFF_BNP   3182720u    // [128][2][64]    BN partial sum/sumsq
// total = 3199104 floats = 12.8 MB

__device__ __forceinline__ float rdlane(float v, int lane) {
  return __int_as_float(__builtin_amdgcn_readlane(__float_as_int(v), lane));
}

// K1: xt = einsum('bchw,co->bohw') + per-block scatter partials; block 256 does inv(Wm Wm^T)
__global__ __launch_bounds__(256) void k1_xt_bins_inv(
    const float* __restrict__ x, const int* __restrict__ index,
    const float* __restrict__ Wft, const float* __restrict__ Wm,
    float* __restrict__ ws)
{
  __shared__ __align__(16) float smem[8704];  // max(64*65+64, 2*64*68) = 34.8KB
  const int blk = blockIdx.x, tid = threadIdx.x;
  if (blk < NB1) {
    float* lds_sums = smem;            // [64][65] padded: bank = (k+o)%32, spreads random k
    float* lds_cnt  = smem + 64 * 65;  // [64]
    for (int i = tid; i < 64 * 65 + 64; i += 256) smem[i] = 0.f;
    __syncthreads();
    const int b    = blk >> 7;
    const int pg   = blk & 127;
    const int lane = tid & 63;
    const int w    = tid >> 6;
    // wave-uniform o-half so Wft loads scalarize (s_load path)
    const int o0 = __builtin_amdgcn_readfirstlane((w >> 1) << 5);
    const int hw = (pg << 7) + ((w & 1) << 6) + lane;
    const float* xp = x + (size_t)b * CIN * HW + hw;
    float acc[32];
#pragma unroll
    for (int j = 0; j < 32; ++j) acc[j] = 0.f;
#pragma unroll 4
    for (int c = 0; c < CIN; ++c) {
      const float xv = xp[(size_t)c * HW];           // coalesced across lanes
      const float4* w4 = (const float4*)(Wft + (c << 6) + o0);  // uniform address
#pragma unroll
      for (int q = 0; q < 8; ++q) {
        const float4 wv = w4[q];
        acc[4*q+0] = fmaf(xv, wv.x, acc[4*q+0]);
        acc[4*q+1] = fmaf(xv, wv.y, acc[4*q+1]);
        acc[4*q+2] = fmaf(xv, wv.z, acc[4*q+2]);
        acc[4*q+3] = fmaf(xv, wv.w, acc[4*q+3]);
      }
    }
    float* xtp = ws + OFF_XT + ((size_t)(b * COUT + o0)) * HW + hw;
#pragma unroll
    for (int j = 0; j < 32; ++j) xtp[(size_t)j * HW] = acc[j];
    const int k = index[b * HW + hw];
#pragma unroll
    for (int j = 0; j < 32; ++j) atomicAdd(&lds_sums[k * 65 + o0 + j], acc[j]);
    if (o0 == 0) atomicAdd(&lds_cnt[k], 1.f);   // each pixel counted once (waves 0,1)
    __syncthreads();
    float* ps = ws + OFF_PS + (size_t)blk * 4096;
    for (int e = tid; e < 4096; e += 256) ps[e] = lds_sums[(e >> 6) * 65 + (e & 63)];
    if (tid < 64) ws[OFF_PC + blk * 64 + tid] = lds_cnt[tid];
  } else {
    // ---- inverse block: cov = Wm Wm^T, then in-place Gauss-Jordan (SPD, no pivoting)
    float* wm  = smem;            // [64][68]
    float* cov = smem + 64 * 68;  // [64][68]
    for (int e = tid; e < 4096; e += 256) wm[(e >> 6) * 68 + (e & 63)] = Wm[e];
    __syncthreads();
    {
      const int i0 = (tid >> 4) << 2, j0 = (tid & 15) << 2;
      float c4[16];
#pragma unroll
      for (int q = 0; q < 16; ++q) c4[q] = 0.f;
      for (int cq = 0; cq < 64; cq += 4) {
        float4 a[4], bb[4];
#pragma unroll
        for (int ii = 0; ii < 4; ++ii) a[ii]  = *(const float4*)&wm[(i0+ii)*68 + cq];
#pragma unroll
        for (int jj = 0; jj < 4; ++jj) bb[jj] = *(const float4*)&wm[(j0+jj)*68 + cq];
#pragma unroll
        for (int ii = 0; ii < 4; ++ii)
#pragma unroll
          for (int jj = 0; jj < 4; ++jj)
            c4[ii*4+jj] = fmaf(a[ii].x, bb[jj].x, fmaf(a[ii].y, bb[jj].y,
                          fmaf(a[ii].z, bb[jj].z, fmaf(a[ii].w, bb[jj].w, c4[ii*4+jj]))));
      }
#pragma unroll
      for (int ii = 0; ii < 4; ++ii)
#pragma unroll
        for (int jj = 0; jj < 4; ++jj)
          cov[(i0+ii)*68 + (j0+jj)] = c4[ii*4+jj];
    }
    __syncthreads();
    if (tid < 64) {
      // lane = row; fully unrolled so all r[] indices are static (registers, no scratch)
      float r[64];
#pragma unroll
      for (int j = 0; j < 64; ++j) r[j] = cov[tid * 68 + j];
#pragma unroll
      for (int k = 0; k < 64; ++k) {
        const float piv = rdlane(r[k], k);
        const float rp  = 1.0f / piv;
        const float a   = (tid == k) ? (rp - 1.0f) : (-r[k] * rp);
#pragma unroll
        for (int j = 0; j < 64; ++j) {
          const float s = rdlane(r[j], k);  // reads pre-update row k (lockstep)
          r[j] = fmaf(a, s, r[j]);
        }
        r[k] = (tid == k) ? rp : a;
      }
#pragma unroll
      for (int j = 0; j < 64; ++j) ws[OFF_INV + tid * 64 + j] = r[j];
    }
  }
}

// K1.5: reduce partials -> means; diag[b][k] = m^T C^-1 m
__global__ __launch_bounds__(64) void k15_means_diag(float* __restrict__ ws)
{
  const int blk = blockIdx.x;            // 0..127 : b = blk>>6, k = blk&63
  const int b = blk >> 6, k = blk & 63, t = threadIdx.x;  // t = o
  const float* ps = ws + OFF_PS;
  float s = 0.f;
#pragma unroll 4
  for (int i = 0; i < 128; ++i)
    s += ps[(size_t)(b * 128 + i) * 4096 + (k << 6) + t];
  const float* pc = ws + OFF_PC;
  float cnt = 0.f;
#pragma unroll 4
  for (int i = 0; i < 128; ++i) cnt += pc[(b * 128 + i) * 64 + k];
  const float denom = cnt + ((cnt == 0.f) ? 1.f : 0.f);
  const float m = s / denom;
  ws[OFF_MEANS + (b * 64 + k) * 64 + t] = m;
  const float* inv = ws + OFF_INV;
  float inner = 0.f;
#pragma unroll
  for (int d = 0; d < 64; ++d) {
    const float md = __shfl(m, d, 64);
    inner = fmaf(inv[t * 64 + d], md, inner);
  }
  float dv = m * inner;
#pragma unroll
  for (int mm = 32; mm > 0; mm >>= 1) dv += __shfl_down(dv, mm, 64);
  if (t == 0) ws[OFF_DIAG + b * 64 + k] = dv;
}

// K2: T = means@inv ; q = diag_i+diag_j-2*T_i.m_j ; adj = exp(-sqrt(max(q,1e-12))) ; AM = adj@means
__global__ __launch_bounds__(256) void k2_adj(float* __restrict__ ws)
{
  __shared__ __align__(16) float means_s[64 * 68];
  __shared__ __align__(16) float inv_s[64 * 68];
  __shared__ __align__(16) float T_s[8 * 68];
  __shared__ __align__(16) float adj_s[8 * 68];
  __shared__ float diag_s[64];
  const int b = blockIdx.x >> 3;
  const int i0 = (blockIdx.x & 7) << 3;   // 8-row chunk
  const int t = threadIdx.x;
  const float* mg = ws + OFF_MEANS + b * 4096;
  for (int e = t; e < 4096; e += 256) means_s[(e >> 6) * 68 + (e & 63)] = mg[e];
  const float* ig = ws + OFF_INV;
  for (int e = t; e < 4096; e += 256) inv_s[(e >> 6) * 68 + (e & 63)] = ig[e];
  if (t < 64) diag_s[t] = ws[OFF_DIAG + b * 64 + t];
  __syncthreads();
  if (t < 128) {
    const int i = t >> 4, d0 = (t & 15) << 2;
    float4 acc = {0.f, 0.f, 0.f, 0.f};
    for (int c = 0; c < 64; ++c) {
      const float mv = means_s[(i0 + i) * 68 + c];
      const float4 iv = *(const float4*)&inv_s[c * 68 + d0];
      acc.x = fmaf(mv, iv.x, acc.x); acc.y = fmaf(mv, iv.y, acc.y);
      acc.z = fmaf(mv, iv.z, acc.z); acc.w = fmaf(mv, iv.w, acc.w);
    }
    *(float4*)&T_s[i * 68 + d0] = acc;
  }
  __syncthreads();
  {
    const int i = t >> 5, jb = t & 31;
#pragma unroll
    for (int jj = 0; jj < 2; ++jj) {
      const int j = jb + (jj << 5);
      float4 p4 = {0.f, 0.f, 0.f, 0.f};
      for (int dq = 0; dq < 64; dq += 4) {
        const float4 tv = *(const float4*)&T_s[i * 68 + dq];
        const float4 mv = *(const float4*)&means_s[j * 68 + dq];
        p4.x = fmaf(tv.x, mv.x, p4.x); p4.y = fmaf(tv.y, mv.y, p4.y);
        p4.z = fmaf(tv.z, mv.z, p4.z); p4.w = fmaf(tv.w, mv.w, p4.w);
      }
      const float p = (p4.x + p4.y) + (p4.z + p4.w);
      const float q = diag_s[i0 + i] + diag_s[j] - 2.f * p;
      adj_s[i * 68 + j] = __expf(-sqrtf(fmaxf(q, 1e-12f)));
    }
  }
  __syncthreads();
  if (t < 128) {
    const int i = t >> 4, oq = (t & 15) << 2;
    float4 am = {0.f, 0.f, 0.f, 0.f};
    for (int j = 0; j < 64; ++j) {
      const float av = adj_s[i * 68 + j];
      const float4 mv = *(const float4*)&means_s[j * 68 + oq];
      am.x = fmaf(av, mv.x, am.x); am.y = fmaf(av, mv.y, am.y);
      am.z = fmaf(av, mv.z, am.z); am.w = fmaf(av, mv.w, am.w);
    }
    *(float4*)(ws + OFF_ADJM + (size_t)(b * 64 + i0 + i) * 64 + oq) = am;
  }
}

// K3: BN partial stats of f = relu(xt + adj_means[idx])
__global__ __launch_bounds__(256) void k3_bnstats(const int* __restrict__ index,
                                                  float* __restrict__ ws)
{
  __shared__ float am_s[64 * 65];
  __shared__ float red[128];
  const int blk = blockIdx.x, t = threadIdx.x;
  const int b = blk >> 6;
  const int hw = ((blk & 63) << 8) + t;
  const float* am = ws + OFF_ADJM + b * 4096;
  for (int e = t; e < 4096; e += 256) am_s[(e >> 6) * 65 + (e & 63)] = am[e];
  if (t < 128) red[t] = 0.f;
  __syncthreads();
  const int k = index[b * HW + hw];
  const float* xtp = ws + OFF_XT + (size_t)b * COUT * HW + hw;
  const int lane = t & 63;
#pragma unroll 2
  for (int o = 0; o < 64; ++o) {
    float f = fmaxf(xtp[(size_t)o * HW] + am_s[k * 65 + o], 0.f);
    float fs = f * f;
#pragma unroll
    for (int m = 1; m < 64; m <<= 1) {
      f  += __shfl_xor(f,  m, 64);
      fs += __shfl_xor(fs, m, 64);
    }
    if (lane == 0) { atomicAdd(&red[o], f); atomicAdd(&red[64 + o], fs); }
  }
  __syncthreads();
  if (t < 128) ws[OFF_BNP + blk * 128 + t] = red[t];
}

// K4: reduce BN partials (redundantly per block, L2-hot) and write normalized output
__global__ __launch_bounds__(256) void k4_out(const int* __restrict__ index,
    const float* __restrict__ gamma, const float* __restrict__ beta,
    const float* __restrict__ ws, float* __restrict__ out)
{
  __shared__ float am_s[64 * 65];
  __shared__ float scale_s[64], shift_s[64];
  const int blk = blockIdx.x, t = threadIdx.x;
  const int b = blk >> 6;
  const int hw = ((blk & 63) << 8) + t;
  const float* am = ws + OFF_ADJM + b * 4096;
  for (int e = t; e < 4096; e += 256) am_s[(e >> 6) * 65 + (e & 63)] = am[e];
  if (t < 64) {
    float s = 0.f, sq = 0.f;
    const float* bnp = ws + OFF_BNP;
#pragma unroll 4
    for (int i = 0; i < 128; ++i) {
      s  += bnp[i * 128 + t];
      sq += bnp[i * 128 + 64 + t];
    }
    const float mean = s * (1.f / 32768.f);
    const float var  = sq * (1.f / 32768.f) - mean * mean;
    const float sc = gamma[t] / sqrtf(var + 1e-5f);
    scale_s[t] = sc;
    shift_s[t] = fmaf(-mean, sc, beta[t]);
  }
  __syncthreads();
  const int k = index[b * HW + hw];
  const float* xtp = ws + OFF_XT + (size_t)b * COUT * HW + hw;
  float* op = out + (size_t)b * COUT * HW + hw;
#pragma unroll 4
  for (int o = 0; o < 64; ++o) {
    const float f = fmaxf(xtp[(size_t)o * HW] + am_s[k * 65 + o], 0.f);
    op[(size_t)o * HW] = fmaf(f, scale_s[o], shift_s[o]);
  }
}

extern "C" void kernel_launch(void* const* d_in, const int* in_sizes, int n_in,
                              void* d_out, int out_size, void* d_ws, size_t ws_size,
                              hipStream_t stream) {
  const float* x     = (const float*)d_in[0];
  const int*   index = (const int*)d_in[1];
  const float* Wft   = (const float*)d_in[2];
  const float* Wm    = (const float*)d_in[3];
  const float* gamma = (const float*)d_in[4];
  const float* beta  = (const float*)d_in[5];
  float* ws  = (float*)d_ws;
  float* out = (float*)d_out;

  k1_xt_bins_inv<<<NB1 + 1, 256, 0, stream>>>(x, index, Wft, Wm, ws);
  k15_means_diag<<<128, 64, 0, stream>>>(ws);
  k2_adj<<<16, 256, 0, stream>>>(ws);
  k3_bnstats<<<128, 256, 0, stream>>>(index, ws);
  k4_out<<<128, 256, 0, stream>>>(index, gamma, beta, ws, out);
}

// Round 2
// 137.790 us; speedup vs baseline: 1.4404x; 1.4404x over previous
//
#include <hip/hip_runtime.h>
#include <hip/hip_bf16.h>

// Problem constants
#define CIN   128
#define COUT  64
#define HW    16384   // 128*128
#define NB1   512     // K1 compute blocks (256 per batch, 64 px each)

typedef __hip_bfloat16 bf16;

// Workspace layout (float offsets) — total 3,186,816 floats = 12.75 MB
#define OFF_XT    0u          // f32 [2][64][16384]  xt
#define OFF_PS    2097152u    // bf16[512][64][64]   partial bin sums (1,048,576 f-equiv)
#define OFF_PC    3145728u    // bf16[512][64]       partial bin counts (16,384 f-equiv)
#define OFF_MEANS 3162112u    // f32 [2][64][64]
#define OFF_DIAG  3170304u    // f32 [2][64]         m^T C^-1 m
#define OFF_INV   3170432u    // f32 [64][64]        inv(cov) (symmetric)
#define OFF_ADJM  3174528u    // f32 [2][64][64]     adj @ means
#define OFF_BNP   3182720u    // f32 [16 og][32 b*tile][8]  BN partials {s0..3,ss0..3}

__device__ __forceinline__ float rdlane(float v, int lane) {
  return __int_as_float(__builtin_amdgcn_readlane(__float_as_int(v), lane));
}

// K1: xt = einsum('bchw,co->bohw') + per-block bin partials; block 512 does inv(Wm Wm^T).
// 512 blocks -> 2 blocks/CU (8 waves/CU). thread = 1 px x 16 o; 8-deep load prefetch.
__global__ __launch_bounds__(256) void k1_xt_bins_inv(
    const float* __restrict__ x, const int* __restrict__ index,
    const float* __restrict__ Wft, const float* __restrict__ Wm,
    float* __restrict__ ws)
{
  __shared__ __align__(16) float smem[8704];  // max(64*65+64, 2*64*68) = 34.8KB
  const int blk = blockIdx.x, tid = threadIdx.x;
  if (blk < NB1) {
    float* lds_sums = smem;            // [64][65] padded
    float* lds_cnt  = smem + 64 * 65;  // [64]
    for (int i = tid; i < 64 * 65 + 64; i += 256) smem[i] = 0.f;
    __syncthreads();
    const int b    = blk >> 8;
    const int pg   = blk & 255;
    const int lane = tid & 63;
    const int og   = tid >> 6;
    const int o0   = __builtin_amdgcn_readfirstlane(og << 4);  // uniform -> s_load Wft
    const int px   = (pg << 6) + lane;
    const float* xp = x + (size_t)b * CIN * HW + px;
    const int k = index[b * HW + px];
    float acc[16];
#pragma unroll
    for (int j = 0; j < 16; ++j) acc[j] = 0.f;
    // software pipeline: 8 x-loads in flight while FMAing previous 8
    float xa[8], xb[8];
#pragma unroll
    for (int u = 0; u < 8; ++u) xa[u] = xp[(size_t)u * HW];
    for (int cb = 0; cb < 128; cb += 8) {
      if (cb + 8 < 128) {
#pragma unroll
        for (int u = 0; u < 8; ++u) xb[u] = xp[(size_t)(cb + 8 + u) * HW];
      }
#pragma unroll
      for (int u = 0; u < 8; ++u) {
        const float xv = xa[u];
        const float4* w4 = (const float4*)(Wft + ((cb + u) << 6) + o0);
        const float4 w0 = w4[0], w1 = w4[1], w2 = w4[2], w3 = w4[3];
        acc[ 0]=fmaf(xv,w0.x,acc[ 0]); acc[ 1]=fmaf(xv,w0.y,acc[ 1]);
        acc[ 2]=fmaf(xv,w0.z,acc[ 2]); acc[ 3]=fmaf(xv,w0.w,acc[ 3]);
        acc[ 4]=fmaf(xv,w1.x,acc[ 4]); acc[ 5]=fmaf(xv,w1.y,acc[ 5]);
        acc[ 6]=fmaf(xv,w1.z,acc[ 6]); acc[ 7]=fmaf(xv,w1.w,acc[ 7]);
        acc[ 8]=fmaf(xv,w2.x,acc[ 8]); acc[ 9]=fmaf(xv,w2.y,acc[ 9]);
        acc[10]=fmaf(xv,w2.z,acc[10]); acc[11]=fmaf(xv,w2.w,acc[11]);
        acc[12]=fmaf(xv,w3.x,acc[12]); acc[13]=fmaf(xv,w3.y,acc[13]);
        acc[14]=fmaf(xv,w3.z,acc[14]); acc[15]=fmaf(xv,w3.w,acc[15]);
      }
#pragma unroll
      for (int u = 0; u < 8; ++u) xa[u] = xb[u];
    }
    float* xtp = ws + OFF_XT + (size_t)(b * COUT + o0) * HW + px;
#pragma unroll
    for (int j = 0; j < 16; ++j) xtp[(size_t)j * HW] = acc[j];
#pragma unroll
    for (int j = 0; j < 16; ++j) atomicAdd(&lds_sums[k * 65 + o0 + j], acc[j]);
    if (og == 0) atomicAdd(&lds_cnt[k], 1.f);   // each pixel counted once
    __syncthreads();
    bf16* pb = (bf16*)(ws + OFF_PS) + (size_t)blk * 4096;
    for (int e = tid; e < 4096; e += 256)
      pb[e] = __float2bfloat16(lds_sums[(e >> 6) * 65 + (e & 63)]);
    if (tid < 64)
      ((bf16*)(ws + OFF_PC))[blk * 64 + tid] = __float2bfloat16(lds_cnt[tid]); // <=64, exact
  } else {
    // ---- inverse block: cov = Wm Wm^T, then in-place Gauss-Jordan (SPD, no pivoting)
    float* wm  = smem;            // [64][68]
    float* cov = smem + 64 * 68;  // [64][68]
    for (int e = tid; e < 4096; e += 256) wm[(e >> 6) * 68 + (e & 63)] = Wm[e];
    __syncthreads();
    {
      const int i0 = (tid >> 4) << 2, j0 = (tid & 15) << 2;
      float c4[16];
#pragma unroll
      for (int q = 0; q < 16; ++q) c4[q] = 0.f;
      for (int cq = 0; cq < 64; cq += 4) {
        float4 a[4], bb[4];
#pragma unroll
        for (int ii = 0; ii < 4; ++ii) a[ii]  = *(const float4*)&wm[(i0+ii)*68 + cq];
#pragma unroll
        for (int jj = 0; jj < 4; ++jj) bb[jj] = *(const float4*)&wm[(j0+jj)*68 + cq];
#pragma unroll
        for (int ii = 0; ii < 4; ++ii)
#pragma unroll
          for (int jj = 0; jj < 4; ++jj)
            c4[ii*4+jj] = fmaf(a[ii].x, bb[jj].x, fmaf(a[ii].y, bb[jj].y,
                          fmaf(a[ii].z, bb[jj].z, fmaf(a[ii].w, bb[jj].w, c4[ii*4+jj]))));
      }
#pragma unroll
      for (int ii = 0; ii < 4; ++ii)
#pragma unroll
        for (int jj = 0; jj < 4; ++jj)
          cov[(i0+ii)*68 + (j0+jj)] = c4[ii*4+jj];
    }
    __syncthreads();
    if (tid < 64) {
      float r[64];
#pragma unroll
      for (int j = 0; j < 64; ++j) r[j] = cov[tid * 68 + j];
#pragma unroll
      for (int k = 0; k < 64; ++k) {
        const float piv = rdlane(r[k], k);
        const float rp  = 1.0f / piv;
        const float a   = (tid == k) ? (rp - 1.0f) : (-r[k] * rp);
#pragma unroll
        for (int j = 0; j < 64; ++j) {
          const float s = rdlane(r[j], k);
          r[j] = fmaf(a, s, r[j]);
        }
        r[k] = (tid == k) ? rp : a;
      }
#pragma unroll
      for (int j = 0; j < 64; ++j) ws[OFF_INV + tid * 64 + j] = r[j];
    }
  }
}

// K1.5: reduce bin partials -> means; diag[b][k] = m^T C^-1 m.
// 128 blocks x 1024 threads: 16 waves, each wave-chunk sums 16 partials.
__global__ __launch_bounds__(1024) void k15_means_diag(float* __restrict__ ws)
{
  __shared__ float red[16 * 64];
  __shared__ float lds_c[4];
  __shared__ float lds_m[64];
  const int blk = blockIdx.x, t = threadIdx.x;
  const int b = blk >> 6, k = blk & 63;
  const int o = t & 63, chunk = t >> 6;
  const bf16* ps = (const bf16*)(ws + OFF_PS);
  float s = 0.f;
#pragma unroll
  for (int s16 = 0; s16 < 16; ++s16) {
    const int i = chunk * 16 + s16;
    s += __bfloat162float(ps[(size_t)(b * 256 + i) * 4096 + (k << 6) + o]);
  }
  red[chunk * 64 + o] = s;
  float cv = 0.f;
  if (t < 256) cv = __bfloat162float(((const bf16*)(ws + OFF_PC))[(b * 256 + t) * 64 + k]);
#pragma unroll
  for (int m = 32; m; m >>= 1) cv += __shfl_xor(cv, m, 64);
  if (t < 256 && (t & 63) == 0) lds_c[t >> 6] = cv;
  __syncthreads();
  if (t < 64) {
    float m_raw = 0.f;
#pragma unroll
    for (int ch = 0; ch < 16; ++ch) m_raw += red[ch * 64 + o];
    const float cnt = lds_c[0] + lds_c[1] + lds_c[2] + lds_c[3];
    const float denom = cnt + ((cnt == 0.f) ? 1.f : 0.f);
    const float m = m_raw / denom;
    ws[OFF_MEANS + (size_t)(b * 64 + k) * 64 + o] = m;
    lds_m[o] = m;
    // inv symmetric: inner_o = sum_d inv[o][d] m[d] = sum_d inv[d][o] m[d] (coalesced)
    float inner = 0.f;
#pragma unroll 8
    for (int d = 0; d < 64; ++d) inner = fmaf(ws[OFF_INV + d * 64 + o], lds_m[d], inner);
    float p = m * inner;
#pragma unroll
    for (int mm = 32; mm; mm >>= 1) p += __shfl_xor(p, mm, 64);
    if (o == 0) ws[OFF_DIAG + b * 64 + k] = p;
  }
}

// K2: T = means@inv ; q = diag_i+diag_j-2*T_i.m_j ; adj = exp(-sqrt(max(q,1e-12))) ; AM = adj@means
__global__ __launch_bounds__(256) void k2_adj(float* __restrict__ ws)
{
  __shared__ __align__(16) float means_s[64 * 68];
  __shared__ __align__(16) float inv_s[64 * 68];
  __shared__ __align__(16) float T_s[8 * 68];
  __shared__ __align__(16) float adj_s[8 * 68];
  __shared__ float diag_s[64];
  const int b = blockIdx.x >> 3;
  const int i0 = (blockIdx.x & 7) << 3;   // 8-row chunk
  const int t = threadIdx.x;
  const float* mg = ws + OFF_MEANS + b * 4096;
  for (int e = t; e < 4096; e += 256) means_s[(e >> 6) * 68 + (e & 63)] = mg[e];
  const float* ig = ws + OFF_INV;
  for (int e = t; e < 4096; e += 256) inv_s[(e >> 6) * 68 + (e & 63)] = ig[e];
  if (t < 64) diag_s[t] = ws[OFF_DIAG + b * 64 + t];
  __syncthreads();
  if (t < 128) {
    const int i = t >> 4, d0 = (t & 15) << 2;
    float4 acc = {0.f, 0.f, 0.f, 0.f};
    for (int c = 0; c < 64; ++c) {
      const float mv = means_s[(i0 + i) * 68 + c];
      const float4 iv = *(const float4*)&inv_s[c * 68 + d0];
      acc.x = fmaf(mv, iv.x, acc.x); acc.y = fmaf(mv, iv.y, acc.y);
      acc.z = fmaf(mv, iv.z, acc.z); acc.w = fmaf(mv, iv.w, acc.w);
    }
    *(float4*)&T_s[i * 68 + d0] = acc;
  }
  __syncthreads();
  {
    const int i = t >> 5, jb = t & 31;
#pragma unroll
    for (int jj = 0; jj < 2; ++jj) {
      const int j = jb + (jj << 5);
      float4 p4 = {0.f, 0.f, 0.f, 0.f};
      for (int dq = 0; dq < 64; dq += 4) {
        const float4 tv = *(const float4*)&T_s[i * 68 + dq];
        const float4 mv = *(const float4*)&means_s[j * 68 + dq];
        p4.x = fmaf(tv.x, mv.x, p4.x); p4.y = fmaf(tv.y, mv.y, p4.y);
        p4.z = fmaf(tv.z, mv.z, p4.z); p4.w = fmaf(tv.w, mv.w, p4.w);
      }
      const float p = (p4.x + p4.y) + (p4.z + p4.w);
      const float q = diag_s[i0 + i] + diag_s[j] - 2.f * p;
      adj_s[i * 68 + j] = __expf(-sqrtf(fmaxf(q, 1e-12f)));
    }
  }
  __syncthreads();
  if (t < 128) {
    const int i = t >> 4, oq = (t & 15) << 2;
    float4 am = {0.f, 0.f, 0.f, 0.f};
    for (int j = 0; j < 64; ++j) {
      const float av = adj_s[i * 68 + j];
      const float4 mv = *(const float4*)&means_s[j * 68 + oq];
      am.x = fmaf(av, mv.x, am.x); am.y = fmaf(av, mv.y, am.y);
      am.z = fmaf(av, mv.z, am.z); am.w = fmaf(av, mv.w, am.w);
    }
    *(float4*)(ws + OFF_ADJM + (size_t)(b * 64 + i0 + i) * 64 + oq) = am;
  }
}

// K3: BN partial stats of f = relu(xt + adj_means[idx]).
// 512 blocks: (b, og of 4 o, tile of 1024 px); thread = float4 px x 4 o.
__global__ __launch_bounds__(256) void k3_bnstats(const int* __restrict__ index,
                                                  float* __restrict__ ws)
{
  __shared__ float4 am_s[64];
  __shared__ float red[8];
  const int blk = blockIdx.x, t = threadIdx.x;
  const int b = blk >> 8, og = (blk >> 4) & 15, tile = blk & 15;
  if (t < 64) am_s[t] = *(const float4*)(ws + OFF_ADJM + (size_t)(b * 64 + t) * 64 + og * 4);
  if (t < 8) red[t] = 0.f;
  __syncthreads();
  const int px0 = (tile << 10) + (t << 2);
  const int4 kv = *(const int4*)(index + b * HW + px0);
  const int kk[4] = {kv.x, kv.y, kv.z, kv.w};
  float4 xtv[4], amv[4];
#pragma unroll
  for (int oj = 0; oj < 4; ++oj)
    xtv[oj] = *(const float4*)(ws + OFF_XT + (size_t)(b * 64 + og * 4 + oj) * HW + px0);
#pragma unroll
  for (int p = 0; p < 4; ++p) amv[p] = am_s[kk[p]];
  float s[4] = {0.f,0.f,0.f,0.f}, ss[4] = {0.f,0.f,0.f,0.f};
#pragma unroll
  for (int oj = 0; oj < 4; ++oj) {
    const float* xf = (const float*)&xtv[oj];
#pragma unroll
    for (int p = 0; p < 4; ++p) {
      const float* af = (const float*)&amv[p];
      const float f = fmaxf(xf[p] + af[oj], 0.f);
      s[oj] += f; ss[oj] = fmaf(f, f, ss[oj]);
    }
  }
#pragma unroll
  for (int m = 1; m < 64; m <<= 1) {
#pragma unroll
    for (int oj = 0; oj < 4; ++oj) {
      s[oj]  += __shfl_xor(s[oj],  m, 64);
      ss[oj] += __shfl_xor(ss[oj], m, 64);
    }
  }
  if ((t & 63) == 0) {
#pragma unroll
    for (int oj = 0; oj < 4; ++oj) {
      atomicAdd(&red[oj], s[oj]);
      atomicAdd(&red[4 + oj], ss[oj]);
    }
  }
  __syncthreads();
  if (t < 8) ws[OFF_BNP + (size_t)(og * 32 + b * 16 + tile) * 8 + t] = red[t];
}

// K4: redundant 1KB BN-final reduce per block, then out = f*scale + shift.
__global__ __launch_bounds__(256) void k4_out(const int* __restrict__ index,
    const float* __restrict__ gamma, const float* __restrict__ beta,
    const float* __restrict__ ws, float* __restrict__ out)
{
  __shared__ float4 am_s[64];
  __shared__ float tmp[8];
  __shared__ float sc_s[4], sh_s[4];
  const int blk = blockIdx.x, t = threadIdx.x;
  const int b = blk >> 8, og = (blk >> 4) & 15, tile = blk & 15;
  if (t < 64) am_s[t] = *(const float4*)(ws + OFF_ADJM + (size_t)(b * 64 + t) * 64 + og * 4);
  if (t < 8) {
    float v = 0.f;
#pragma unroll 4
    for (int i = 0; i < 32; ++i) v += ws[OFF_BNP + (size_t)(og * 32 + i) * 8 + t];
    tmp[t] = v;
  }
  if (t < 4) {  // same wave as tmp writers: per-wave LDS ordering suffices
    const float mean = tmp[t] * (1.f / 32768.f);
    const float var  = tmp[4 + t] * (1.f / 32768.f) - mean * mean;
    const float sc = gamma[og * 4 + t] * rsqrtf(var + 1e-5f);
    sc_s[t] = sc;
    sh_s[t] = fmaf(-mean, sc, beta[og * 4 + t]);
  }
  __syncthreads();
  const int px0 = (tile << 10) + (t << 2);
  const int4 kv = *(const int4*)(index + b * HW + px0);
  const int kk[4] = {kv.x, kv.y, kv.z, kv.w};
  float4 xtv[4], amv[4];
#pragma unroll
  for (int oj = 0; oj < 4; ++oj)
    xtv[oj] = *(const float4*)(ws + OFF_XT + (size_t)(b * 64 + og * 4 + oj) * HW + px0);
#pragma unroll
  for (int p = 0; p < 4; ++p) amv[p] = am_s[kk[p]];
#pragma unroll
  for (int oj = 0; oj < 4; ++oj) {
    const float* xf = (const float*)&xtv[oj];
    float4 o4;
    float* of = (float*)&o4;
#pragma unroll
    for (int p = 0; p < 4; ++p) {
      const float* af = (const float*)&amv[p];
      const float f = fmaxf(xf[p] + af[oj], 0.f);
      of[p] = fmaf(f, sc_s[oj], sh_s[oj]);
    }
    *(float4*)(out + (size_t)(b * 64 + og * 4 + oj) * HW + px0) = o4;
  }
}

extern "C" void kernel_launch(void* const* d_in, const int* in_sizes, int n_in,
                              void* d_out, int out_size, void* d_ws, size_t ws_size,
                              hipStream_t stream) {
  const float* x     = (const float*)d_in[0];
  const int*   index = (const int*)d_in[1];
  const float* Wft   = (const float*)d_in[2];
  const float* Wm    = (const float*)d_in[3];
  const float* gamma = (const float*)d_in[4];
  const float* beta  = (const float*)d_in[5];
  float* ws  = (float*)d_ws;
  float* out = (float*)d_out;

  k1_xt_bins_inv<<<NB1 + 1, 256, 0, stream>>>(x, index, Wft, Wm, ws);
  k15_means_diag<<<128, 1024, 0, stream>>>(ws);
  k2_adj<<<16, 256, 0, stream>>>(ws);
  k3_bnstats<<<512, 256, 0, stream>>>(index, ws);
  k4_out<<<512, 256, 0, stream>>>(index, gamma, beta, ws, out);
}